// Round 7
// baseline (1993.878 us; speedup 1.0000x reference)
//
#include <hip/hip_runtime.h>

#define BT   (512*256)
// hbuf layout (shorts): zeros @0..127, b0 h @128..255, b1 h @288..415
#define HB0  128
#define HB1  288
#define HLEN 448

using short8  = __attribute__((ext_vector_type(8))) short;
using floatx4 = __attribute__((ext_vector_type(4))) float;

__device__ inline unsigned short f2bf(float f){
  unsigned int u = __float_as_uint(f);
  u += 0x7FFFu + ((u >> 16) & 1u);          // RNE
  return (unsigned short)(u >> 16);
}
__device__ inline float bf2f(unsigned short u){
  return __uint_as_float(((unsigned int)u) << 16);
}
__device__ inline float rcpf(float x){ return __builtin_amdgcn_rcpf(x); }

// 128 blocks x 512 threads = 2 independent groups x 4 waves. Each group runs
// its own batch-pair chain with its own LDS-counter sync (never __syncthreads
// after init), so the groups drift into anti-phase on each SIMD: one group's
// MFMA bursts fill the other's serial phases. Weights stay in VGPRs (<=256,
// launch_bounds(512,2)) -- round 6's regression was the 128-VGPR spill.
__global__ __launch_bounds__(512,2) void k_seq(
    const float* __restrict__ in,
    const float* __restrict__ Wih,  const float* __restrict__ Whh,
    const float* __restrict__ bih,  const float* __restrict__ bhh,
    const float* __restrict__ fc1w, const float* __restrict__ fc1b,
    const float* __restrict__ fc2w, const float* __restrict__ fc2b,
    const float* __restrict__ i1w,  const float* __restrict__ i1b,
    const float* __restrict__ i3w,  const float* __restrict__ i3b,
    const float* __restrict__ scw,  const float* __restrict__ zonew,
    float* __restrict__ out)
{
  __shared__ __align__(16) unsigned short hbuf[2][2][HLEN];  // 3584 B
  __shared__ __align__(16) unsigned short xg[2][8192];       // 32 KB bf16 gates (+ int scratch)
  __shared__ __align__(16) unsigned short wihl[512*8];       // 8 KB  bf16 W_ih rows (padded)
  __shared__ __align__(8)  unsigned short toutl[2][512];     // 2 KB  bf16 TOut history
  __shared__ __align__(16) unsigned short exl[2][2048];      // 8 KB  bf16 Ext_X cols
  __shared__ float t0l  [2][512];                            // 4 KB
  __shared__ float hvitl[2][512];                            // 4 KB
  __shared__ float parts[2][8];                              // 64 B  fc2 wave-partials
  __shared__ unsigned int ctr[32];                           // 128 B

  const int tid = threadIdx.x;
  const int g   = tid >> 8;             // group 0/1
  const int t   = tid & 255;
  const int wv  = t >> 6;
  const int ln  = t & 63;
  const int l15 = ln & 15;
  const int quad= ln >> 4;
  const int vbb = blockIdx.x*2 + g;     // virtual block 0..255

  // ---- init (one full-block barrier only) ----
  {
    int r = tid;                        // 512 rows, 512 threads
    #pragma unroll
    for(int c=0;c<8;c++) wihl[r*8+c] = (c<5)? f2bf(Wih[r*5+c]) : (unsigned short)0;
  }
  for(int p=t; p<512; p+=256){
    int b=p>>8, tt=p&255;
    const float* row = in + (2*vbb+b)*1792 + tt*7;
    t0l[g][p] = row[0];
    exl[g][p*4+0]=f2bf(row[1]); exl[g][p*4+1]=f2bf(row[2]);
    exl[g][p*4+2]=f2bf(row[3]); exl[g][p*4+3]=f2bf(row[4]);
  }
  for(int p=t; p<2*HLEN; p+=256) ((unsigned short*)hbuf[g])[p]=0;
  hbuf[g][0][HB0 + (t>>7)*(HB1-HB0) + (t&127)] = 0x3F80;     // h = 1.0
  if(t<16) toutl[g][(t>>3)*256+(t&7)] = f2bf(in[(2*vbb+(t>>3))*1792+(t&7)*7]);
  if(t==0) ctr[g*16]=0;
  float* lw4 = (float*)&xg[g][0];       // int-module scratch (region reused later)
  float* l3  = lw4 + 512;
  if(t<128){
    lw4[t*4+0]=i1w[t*3+0]; lw4[t*4+1]=i1w[t*3+1];
    lw4[t*4+2]=i1w[t*3+2]; lw4[t*4+3]=i1b[t];
    l3[t]=i3w[t];
  }
  __syncthreads();

  // ---- fused int module (per group) ----
  {
    const float b30=i3b[0], sc0=scw[0];
    #pragma unroll
    for(int b=0;b<2;b++){
      const float* row = in + (2*vbb+b)*1792 + t*7;
      float x0=row[3],x1=row[4],x2=row[5], acc=0.f;
      #pragma unroll 8
      for(int j=0;j<128;j++){
        float r=fmaxf(lw4[j*4]*x0+lw4[j*4+1]*x1+lw4[j*4+2]*x2+lw4[j*4+3],0.f);
        acc += r*l3[j];
      }
      float v = rcpf(1.f+__expf(-(acc+b30)))*sc0;
      float itv = (t<8)?0.f:v;
      int gb = 2*vbb+b;
      hvitl[g][b*256+t] = row[6] + itv;
      out[3*BT+gb*256+t]=itv;            // Int_list
      out[BT+gb*256+t]=row[6];           // HVAC_list
      if(t<8){ out[gb*256+t]=row[0]; out[2*BT+gb*256+t]=0.f; }
    }
  }

  // ---- resident weight fragments (wfr + ffr only: ~160 VGPR) ----
  short8 wfr[4][2][4];   // [gate][hh][Kchunk], n = 128g + 32wv + 16hh + l15
  short8 ffr[2][4];
  float  bsum[4][2];
  #pragma unroll
  for(int gg=0;gg<4;gg++){
    #pragma unroll
    for(int hh=0;hh<2;hh++){
      int n = 128*gg + 32*wv + 16*hh + l15;
      bsum[gg][hh] = bih[n]+bhh[n];
      #pragma unroll
      for(int Q=0;Q<4;Q++){
        short8 f;
        #pragma unroll
        for(int j=0;j<8;j++) f[j]=(short)f2bf(Whh[n*128 + Q*32 + quad*8 + j]);
        wfr[gg][hh][Q]=f;
      }
    }
  }
  #pragma unroll
  for(int hh=0;hh<2;hh++){
    int n = 32*wv + 16*hh + l15;
    #pragma unroll
    for(int Q=0;Q<4;Q++){
      short8 f;
      #pragma unroll
      for(int j=0;j<8;j++) f[j]=(short)f2bf(fc1w[n*128 + Q*32 + quad*8 + j]);
      ffr[hh][Q]=f;
    }
  }

  // ---- per-lane persistent scalars ----
  const int  u     = 32*wv + 16*(quad>>1) + l15;
  const int  bm    = quad & 1;
  const bool hi2   = quad >= 2;
  const int  aoff  = ((l15&3)==0) ? (HB0 + ((l15>>2)&1)*(HB1-HB0) + quad*8)
                                  : (quad*8);
  const int  xbase = bm*512 + u;
  const int  hwoff = HB0 + bm*(HB1-HB0) + u;
  const float fb    = fc1b[u];
  const float fcw_u = fc2w[u];
  const float fc2b0 = fc2b[0];
  const float zwv   = zonew[0];
  const floatx4 ZV  = {0.f,0.f,0.f,0.f};
  const short8  Z8  = 0;
  float E0 = in[(2*vbb)*1792 + 56];     // E carried in EVERY lane's registers
  float E1 = in[(2*vbb+1)*1792 + 56];
  float c0 = 1.f;

  // ---- group-local sync: LDS counter + s_sleep poll, lgkm-only fence ----
  unsigned int tgt = 0;
  volatile unsigned int* vct = (volatile unsigned int*)&ctr[g*16];
  #define GSYNC() do{ tgt += 4;                                           \
      __builtin_amdgcn_s_waitcnt(0xc07f); asm volatile("" ::: "memory");  \
      if(ln==0) atomicAdd((unsigned int*)&ctr[g*16], 1u);                 \
      if(*vct < tgt){ do{ __builtin_amdgcn_s_sleep(1); }while(*vct < tgt);} \
      asm volatile("" ::: "memory"); }while(0)

  GSYNC();   // int-module scratch retired -> xg reusable

  #pragma unroll 1
  for(int i=8;i<256;i++){
    // ===== phase A (no preceding sync): TOut, embed in regs, x-MFMA =====
    if(t==0){
      toutl[g][i]     = f2bf(E0);
      toutl[g][256+i] = f2bf(E1);
      out[(2*vbb)*256+i]   = E0;                       // TOut
      out[(2*vbb+1)*256+i] = E1;
    }
    {
      short8 ea = Z8;
      if(quad==0){
        int bE=l15>>3, kk=l15&7, p=i-7+kk;
        float t0v = t0l[g][bE*256+p];
        float tos = (p==i) ? (bE? E1:E0) : bf2f(toutl[g][bE*256+p]);
        float tmix;
        if(i<128){
          float ratio=(float)i*0.0078125f;
          tmix = t0v*ratio + tos*(1.f-ratio);
        } else tmix = tos;
        ea[0]=(short)f2bf(tmix);
        ea[1]=(short)exl[g][(bE*256+p)*4+0]; ea[2]=(short)exl[g][(bE*256+p)*4+1];
        ea[3]=(short)exl[g][(bE*256+p)*4+2]; ea[4]=(short)exl[g][(bE*256+p)*4+3];
      }
      #pragma unroll
      for(int gg=0;gg<4;gg++){
        #pragma unroll
        for(int hh=0;hh<2;hh++){
          short8 xb = Z8;
          if(quad==0) xb = *(const short8*)&wihl[(128*gg+32*wv+16*hh+l15)*8];
          floatx4 z=__builtin_amdgcn_mfma_f32_16x16x32_bf16(ea, xb, ZV,0,0,0);
          #pragma unroll
          for(int r=0;r<4;r++){
            int m=4*quad+r;               // m = b*8+k
            xg[g][(m&7)*1024 + (m>>3)*512 + 128*gg + 32*wv+16*hh+l15]
              = f2bf(z[r]+bsum[gg][hh]);
          }
        }
      }
    }
    GSYNC();

    // ===== 8 inner LSTM steps =====
    #pragma unroll
    for(int k=0;k<8;k++){
      float xv0=bf2f(xg[g][k*1024+xbase    ]);
      float xv1=bf2f(xg[g][k*1024+xbase+128]);
      float xv2=bf2f(xg[g][k*1024+xbase+256]);
      float xv3=bf2f(xg[g][k*1024+xbase+384]);
      const unsigned short* ab = &hbuf[g][k&1][0] + aoff;
      short8 a0=*(const short8*)(ab);
      short8 a1=*(const short8*)(ab+32);
      short8 a2=*(const short8*)(ab+64);
      short8 a3=*(const short8*)(ab+96);
      floatx4 acc[4][2];
      #pragma unroll
      for(int gg=0;gg<4;gg++){
        #pragma unroll
        for(int hh=0;hh<2;hh++){
          floatx4 z=__builtin_amdgcn_mfma_f32_16x16x32_bf16(a0,wfr[gg][hh][0],ZV,0,0,0);
          z=__builtin_amdgcn_mfma_f32_16x16x32_bf16(a1,wfr[gg][hh][1],z,0,0,0);
          z=__builtin_amdgcn_mfma_f32_16x16x32_bf16(a2,wfr[gg][hh][2],z,0,0,0);
          z=__builtin_amdgcn_mfma_f32_16x16x32_bf16(a3,wfr[gg][hh][3],z,0,0,0);
          acc[gg][hh]=z;
        }
      }
      float gi=(hi2?acc[0][1][0]:acc[0][0][0])+xv0;
      float gf=(hi2?acc[1][1][0]:acc[1][0][0])+xv1;
      float gg2=(hi2?acc[2][1][0]:acc[2][0][0])+xv2;
      float go=(hi2?acc[3][1][0]:acc[3][0][0])+xv3;
      float ef =__expf(-gf);
      float egi=__expf(-gi);
      float egg=__expf(-2.f*gg2);
      float sf = rcpf(1.f+ef);
      float itn=(1.f-egg)*rcpf((1.f+egi)*(1.f+egg));
      c0 = sf*c0 + itn;
      float ego=__expf(-go);
      float ec =__expf(-2.f*c0);
      float hv2=(1.f-ec)*rcpf((1.f+ego)*(1.f+ec));
      hbuf[g][(k+1)&1][hwoff]=f2bf(hv2);
      GSYNC();
    }

    // ===== fc1 + in-register fc2 partial reduce =====
    {
      const unsigned short* ab = &hbuf[g][0][0] + aoff;
      short8 a0=*(const short8*)(ab);
      short8 a1=*(const short8*)(ab+32);
      short8 a2=*(const short8*)(ab+64);
      short8 a3=*(const short8*)(ab+96);
      floatx4 fa[2];
      #pragma unroll
      for(int hh=0;hh<2;hh++){
        floatx4 z=__builtin_amdgcn_mfma_f32_16x16x32_bf16(a0,ffr[hh][0],ZV,0,0,0);
        z=__builtin_amdgcn_mfma_f32_16x16x32_bf16(a1,ffr[hh][1],z,0,0,0);
        z=__builtin_amdgcn_mfma_f32_16x16x32_bf16(a2,ffr[hh][2],z,0,0,0);
        z=__builtin_amdgcn_mfma_f32_16x16x32_bf16(a3,ffr[hh][3],z,0,0,0);
        fa[hh]=z;
      }
      float fv = hi2 ? fa[1][0] : fa[0][0];
      float pv = fmaxf(fv+fb,0.f)*fcw_u;
      float v0 = bm ? 0.f : pv;
      float v1 = bm ? pv  : 0.f;
      #pragma unroll
      for(int off=32; off; off>>=1){
        v0 += __shfl_xor(v0, off, 64);
        v1 += __shfl_xor(v1, off, 64);
      }
      if(ln==0){ parts[g][wv*2]=v0; parts[g][wv*2+1]=v1; }
    }
    GSYNC();

    // ===== fc2 total + E update, computed redundantly by EVERY lane =====
    {
      float ext0 = parts[g][0]+parts[g][2]+parts[g][4]+parts[g][6]+fc2b0;
      float ext1 = parts[g][1]+parts[g][3]+parts[g][5]+parts[g][7]+fc2b0;
      float tot0 = ext0 + hvitl[g][i];
      float tot1 = ext1 + hvitl[g][256+i];
      if(i<128){
        float ratio=(float)i*0.0078125f;
        E0 = ratio*t0l[g][i]     + (1.f-ratio)*E0 + tot0*zwv;
        E1 = ratio*t0l[g][256+i] + (1.f-ratio)*E1 + tot1*zwv;
      } else {
        E0 += tot0*zwv;
        E1 += tot1*zwv;
      }
      if(t==0){
        out[2*BT+(2*vbb)*256+i]   = ext0;              // Ext_list
        out[2*BT+(2*vbb+1)*256+i] = ext1;
      }
    }
    // no sync needed: parts/xg/hbuf are only rewritten after the next GSYNCs
  }
  #undef GSYNC
}

extern "C" void kernel_launch(void* const* d_in, const int* in_sizes, int n_in,
                              void* d_out, int out_size, void* d_ws, size_t ws_size,
                              hipStream_t stream)
{
  const float* in   = (const float*)d_in[0];
  const float* Wih  = (const float*)d_in[1];
  const float* Whh  = (const float*)d_in[2];
  const float* bih  = (const float*)d_in[3];
  const float* bhh  = (const float*)d_in[4];
  const float* fc1w = (const float*)d_in[5];
  const float* fc1b = (const float*)d_in[6];
  const float* fc2w = (const float*)d_in[7];
  const float* fc2b = (const float*)d_in[8];
  const float* i1w  = (const float*)d_in[9];
  const float* i1b  = (const float*)d_in[10];
  const float* i3w  = (const float*)d_in[11];
  const float* i3b  = (const float*)d_in[12];
  const float* scw  = (const float*)d_in[13];
  const float* zw   = (const float*)d_in[14];
  float* out = (float*)d_out;

  k_seq<<<dim3(128), dim3(512), 0, stream>>>(in, Wih, Whh, bih, bhh,
                                             fc1w, fc1b, fc2w, fc2b,
                                             i1w, i1b, i3w, i3b, scw, zw, out);
}

// Round 9
// 1228.145 us; speedup vs baseline: 1.6235x; 1.6235x over previous
//
#include <hip/hip_runtime.h>

#define BT   (512*256)
// hbuf layout (shorts): zeros @0..127, b0 h @128..255, b1 h @288..415
#define HB0  128
#define HB1  288
#define HLEN 448

using short8  = __attribute__((ext_vector_type(8))) short;
using floatx4 = __attribute__((ext_vector_type(4))) float;

__device__ inline unsigned short f2bf(float f){
  unsigned int u = __float_as_uint(f);
  u += 0x7FFFu + ((u >> 16) & 1u);          // RNE
  return (unsigned short)(u >> 16);
}
__device__ inline float bf2f(unsigned short u){
  return __uint_as_float(((unsigned int)u) << 16);
}
__device__ inline float rcpf(float x){ return __builtin_amdgcn_rcpf(x); }

// 256 blocks x 512 threads = 8 waves (2/SIMD), __launch_bounds__(512,1) ->
// 256-VGPR cap (the (512,2) variants were capped at 128 and spilled weights
// to scratch: VGPR_Count=128, WRITE_SIZE~60MB).  Wave wv owns units
// 16wv..16wv+15 x ALL 4 gates (wfr = 64 VGPRs). A rows {0,4,8,12} =
// {b0,b1,b0,b1}: lane(quad,l15) gets gates of (batch=quad&1, unit=16wv+l15)
// natively in reg0 of acc[g]; quad2/3 compute duplicate cells (no masking,
// single nonlinearity chain).  Two waves per SIMD fill each other's serial
// phases (read latency, transcendentals, barrier slack) with MFMA bursts.
// Race-free toutl protocol: toutl[i+1] is written at END of iter i (+barrier),
// so phase A is read-only (fixes round 8's replay divergence).
__global__ __launch_bounds__(512,1) void k_seq(
    const float* __restrict__ in,
    const float* __restrict__ Wih,  const float* __restrict__ Whh,
    const float* __restrict__ bih,  const float* __restrict__ bhh,
    const float* __restrict__ fc1w, const float* __restrict__ fc1b,
    const float* __restrict__ fc2w, const float* __restrict__ fc2b,
    const float* __restrict__ i1w,  const float* __restrict__ i1b,
    const float* __restrict__ i3w,  const float* __restrict__ i3b,
    const float* __restrict__ scw,  const float* __restrict__ zonew,
    float* __restrict__ out)
{
  __shared__ __align__(16) unsigned short hbuf[2][HLEN];   // 1792 B
  __shared__ __align__(16) unsigned short xg[8192];        // 16 KB bf16 gates (+init scratch)
  __shared__ __align__(8)  unsigned short toutl[512];      // bf16 TOut history [b][256]
  __shared__ __align__(8)  unsigned short extl[512];       // bf16 Ext results [b][256]
  __shared__ __align__(16) unsigned short exl[2048];       // bf16 Ext_X cols [b*256+t][4]
  __shared__ float t0l[512];                               // T0 f32
  __shared__ float hvitl[512];                             // HVAC + int_all f32
  __shared__ float parts[16];                              // fc2 wave partials [wv][b]

  const int tid = threadIdx.x;
  const int wv  = tid >> 6;             // 0..7
  const int ln  = tid & 63;
  const int l15 = ln & 15;
  const int quad= ln >> 4;
  const int bb  = blockIdx.x;

  // ---- init: stage per-block tables (512 threads, one entry each) ----
  {
    int b=tid>>8, tt=tid&255;
    const float* row = in + (2*bb+b)*1792 + tt*7;
    t0l[tid] = row[0];
    exl[tid*4+0]=f2bf(row[1]); exl[tid*4+1]=f2bf(row[2]);
    exl[tid*4+2]=f2bf(row[3]); exl[tid*4+3]=f2bf(row[4]);
  }
  for(int p=tid; p<2*HLEN; p+=512) ((unsigned short*)hbuf)[p]=0;
  if(tid<16) toutl[(tid>>3)*256+(tid&7)] = f2bf(in[(2*bb+(tid>>3))*1792+(tid&7)*7]);
  float* lw4 = (float*)&xg[0];          // int-module scratch (region reused later)
  float* l3  = lw4 + 512;
  if(tid<128){
    lw4[tid*4+0]=i1w[tid*3+0]; lw4[tid*4+1]=i1w[tid*3+1];
    lw4[tid*4+2]=i1w[tid*3+2]; lw4[tid*4+3]=i1b[tid];
    l3[tid]=i3w[tid];
  }
  __syncthreads();
  if(tid<256) hbuf[0][HB0 + (tid>>7)*(HB1-HB0) + (tid&127)] = 0x3F80;  // h = 1.0

  // ---- fused int module (one (b,t) per thread) ----
  {
    const float b30=i3b[0], sc0=scw[0];
    int b=tid>>8, t=tid&255;
    const float* row = in + (2*bb+b)*1792 + t*7;
    float x0=row[3],x1=row[4],x2=row[5], acc=0.f;
    #pragma unroll 8
    for(int j=0;j<128;j++){
      float r=fmaxf(lw4[j*4]*x0+lw4[j*4+1]*x1+lw4[j*4+2]*x2+lw4[j*4+3],0.f);
      acc += r*l3[j];
    }
    float v = rcpf(1.f+__expf(-(acc+b30)))*sc0;
    float itv = (t<8)?0.f:v;
    int gb = 2*bb+b;
    hvitl[tid] = row[6] + itv;
    out[3*BT+gb*256+t]=itv;              // Int_list
    out[BT+gb*256+t]=row[6];             // HVAC_list
    if(t<8){ out[gb*256+t]=row[0]; out[2*BT+gb*256+t]=0.f; }
  }

  // ---- resident weight fragments (~100 VGPR of weights, cap 256) ----
  short8 wfr[4][4];      // [gate][Kchunk], n = 128g + 16wv + l15
  short8 xfr[4];         // W_ih, K=32 pad (5 valid)
  short8 ffr[4];         // fc1, n2 = 16wv + l15
  float  bsum[4];
  #pragma unroll
  for(int g=0;g<4;g++){
    int n = 128*g + 16*wv + l15;
    bsum[g] = bih[n]+bhh[n];
    #pragma unroll
    for(int Q=0;Q<4;Q++){
      short8 f;
      #pragma unroll
      for(int j=0;j<8;j++) f[j]=(short)f2bf(Whh[n*128 + Q*32 + quad*8 + j]);
      wfr[g][Q]=f;
    }
    short8 f;
    #pragma unroll
    for(int j=0;j<8;j++){ int kk=quad*8+j; f[j]=(short)f2bf(kk<5?Wih[n*5+kk]:0.f); }
    xfr[g]=f;
  }
  {
    int n2 = 16*wv + l15;
    #pragma unroll
    for(int Q=0;Q<4;Q++){
      short8 f;
      #pragma unroll
      for(int j=0;j<8;j++) f[j]=(short)f2bf(fc1w[n2*128 + Q*32 + quad*8 + j]);
      ffr[Q]=f;
    }
  }

  // ---- per-lane persistent scalars ----
  const int  u     = 16*wv + l15;           // this lane's unit
  const int  bm    = quad & 1;              // this lane's batch (quad2/3 dup)
  const int  aoff  = ((l15&3)==0) ? (HB0 + ((l15>>2)&1)*(HB1-HB0) + quad*8)
                                  : (quad*8);              // zero region
  const int  xbase = bm*512 + u;
  const int  hwoff = HB0 + bm*(HB1-HB0) + u;
  const float fb    = fc1b[u];
  const float fcw_u = fc2w[u];
  const float fc2b0 = fc2b[0];
  const float zwv   = zonew[0];
  const floatx4 ZV  = {0.f,0.f,0.f,0.f};
  const short8  Z8  = 0;
  float E0 = in[(2*bb)*1792 + 56];          // E in EVERY lane's registers
  float E1 = in[(2*bb+1)*1792 + 56];
  float c0 = 1.f;
  if(tid==0){ toutl[8]=f2bf(E0); toutl[256+8]=f2bf(E1); }  // TOut[:,8] seed
  __syncthreads();                          // int scratch retired, toutl seeded

  #pragma unroll 1
  for(int i=8;i<256;i++){
    // ===== phase A (read-only on shared): embed in regs, x-MFMA =====
    {
      short8 ea = Z8;
      if(quad==0){
        int bE=l15>>3, kk=l15&7, p=i-7+kk;
        float tos = bf2f(toutl[bE*256+p]);       // p==i pre-written last iter
        float tmix;
        if(i<128){
          float ratio=(float)i*0.0078125f;
          tmix = t0l[bE*256+p]*ratio + tos*(1.f-ratio);
        } else tmix = tos;
        ea[0]=(short)f2bf(tmix);
        ea[1]=(short)exl[(bE*256+p)*4+0]; ea[2]=(short)exl[(bE*256+p)*4+1];
        ea[3]=(short)exl[(bE*256+p)*4+2]; ea[4]=(short)exl[(bE*256+p)*4+3];
      }
      #pragma unroll
      for(int g=0;g<4;g++){
        floatx4 z=__builtin_amdgcn_mfma_f32_16x16x32_bf16(ea, xfr[g], ZV,0,0,0);
        #pragma unroll
        for(int r=0;r<4;r++){
          int m=4*quad+r;                    // m = b*8+k
          xg[(m&7)*1024 + (m>>3)*512 + 128*g + u] = f2bf(z[r]+bsum[g]);
        }
      }
    }
    __syncthreads();

    // ===== 8 inner LSTM steps: 16 MFMA/wave, single nonlin chain =====
    #pragma unroll
    for(int k=0;k<8;k++){
      float xv0=bf2f(xg[k*1024+xbase    ]);
      float xv1=bf2f(xg[k*1024+xbase+128]);
      float xv2=bf2f(xg[k*1024+xbase+256]);
      float xv3=bf2f(xg[k*1024+xbase+384]);
      const unsigned short* ab = &hbuf[k&1][0] + aoff;
      short8 a0=*(const short8*)(ab);
      short8 a1=*(const short8*)(ab+32);
      short8 a2=*(const short8*)(ab+64);
      short8 a3=*(const short8*)(ab+96);
      floatx4 acc[4];
      #pragma unroll
      for(int g=0;g<4;g++){
        floatx4 z=__builtin_amdgcn_mfma_f32_16x16x32_bf16(a0,wfr[g][0],ZV,0,0,0);
        z=__builtin_amdgcn_mfma_f32_16x16x32_bf16(a1,wfr[g][1],z,0,0,0);
        z=__builtin_amdgcn_mfma_f32_16x16x32_bf16(a2,wfr[g][2],z,0,0,0);
        z=__builtin_amdgcn_mfma_f32_16x16x32_bf16(a3,wfr[g][3],z,0,0,0);
        acc[g]=z;
      }
      float gi=acc[0][0]+xv0;
      float gf=acc[1][0]+xv1;
      float gg=acc[2][0]+xv2;
      float go=acc[3][0]+xv3;
      float ef =__expf(-gf);
      float egi=__expf(-gi);
      float egg=__expf(-2.f*gg);
      float sf = rcpf(1.f+ef);
      float itn=(1.f-egg)*rcpf((1.f+egi)*(1.f+egg));
      c0 = sf*c0 + itn;
      float ego=__expf(-go);
      float ec =__expf(-2.f*c0);
      float hv2=(1.f-ec)*rcpf((1.f+ego)*(1.f+ec));
      hbuf[(k+1)&1][hwoff] = f2bf(hv2);      // quad2/3 dup-write same value
      __syncthreads();
    }

    // ===== fc1 + in-register fc2 partial reduce =====
    {
      const unsigned short* ab = &hbuf[0][0] + aoff;
      short8 a0=*(const short8*)(ab);
      short8 a1=*(const short8*)(ab+32);
      short8 a2=*(const short8*)(ab+64);
      short8 a3=*(const short8*)(ab+96);
      floatx4 z=__builtin_amdgcn_mfma_f32_16x16x32_bf16(a0,ffr[0],ZV,0,0,0);
      z=__builtin_amdgcn_mfma_f32_16x16x32_bf16(a1,ffr[1],z,0,0,0);
      z=__builtin_amdgcn_mfma_f32_16x16x32_bf16(a2,ffr[2],z,0,0,0);
      z=__builtin_amdgcn_mfma_f32_16x16x32_bf16(a3,ffr[3],z,0,0,0);
      float pv = fmaxf(z[0]+fb,0.f)*fcw_u;
      float v0 = (quad==0) ? pv : 0.f;       // quad2/3 dups excluded
      float v1 = (quad==1) ? pv : 0.f;
      #pragma unroll
      for(int off=32; off; off>>=1){
        v0 += __shfl_xor(v0, off, 64);
        v1 += __shfl_xor(v1, off, 64);
      }
      if(ln==0){ parts[wv*2]=v0; parts[wv*2+1]=v1; }
    }
    __syncthreads();

    // ===== fc2 total + E update, redundantly by EVERY lane =====
    {
      float ext0 = parts[0]+parts[2]+parts[4]+parts[6]
                 + parts[8]+parts[10]+parts[12]+parts[14] + fc2b0;
      float ext1 = parts[1]+parts[3]+parts[5]+parts[7]
                 + parts[9]+parts[11]+parts[13]+parts[15] + fc2b0;
      float tot0 = ext0 + hvitl[i];
      float tot1 = ext1 + hvitl[256+i];
      if(i<128){
        float ratio=(float)i*0.0078125f;
        E0 = ratio*t0l[i]     + (1.f-ratio)*E0 + tot0*zwv;
        E1 = ratio*t0l[256+i] + (1.f-ratio)*E1 + tot1*zwv;
      } else {
        E0 += tot0*zwv;
        E1 += tot1*zwv;
      }
      if(tid==0){
        extl[i]     = f2bf(ext0);
        extl[256+i] = f2bf(ext1);
        if(i<255){                            // TOut[:,i+1] = E (start of i+1)
          toutl[i+1]     = f2bf(E0);
          toutl[257+i]   = f2bf(E1);
        }
      }
    }
    __syncthreads();                          // publish toutl/extl before reads
  }

  // ===== flush TOut / Ext_list from LDS =====
  for(int p=tid; p<496; p+=512){
    int b = (p>=248) ? 1 : 0;
    int i2 = p - b*248 + 8;
    int gb = 2*bb + b;
    out[gb*256+i2]      = bf2f(toutl[b*256+i2]);
    out[2*BT+gb*256+i2] = bf2f(extl[b*256+i2]);
  }
}

extern "C" void kernel_launch(void* const* d_in, const int* in_sizes, int n_in,
                              void* d_out, int out_size, void* d_ws, size_t ws_size,
                              hipStream_t stream)
{
  const float* in   = (const float*)d_in[0];
  const float* Wih  = (const float*)d_in[1];
  const float* Whh  = (const float*)d_in[2];
  const float* bih  = (const float*)d_in[3];
  const float* bhh  = (const float*)d_in[4];
  const float* fc1w = (const float*)d_in[5];
  const float* fc1b = (const float*)d_in[6];
  const float* fc2w = (const float*)d_in[7];
  const float* fc2b = (const float*)d_in[8];
  const float* i1w  = (const float*)d_in[9];
  const float* i1b  = (const float*)d_in[10];
  const float* i3w  = (const float*)d_in[11];
  const float* i3b  = (const float*)d_in[12];
  const float* scw  = (const float*)d_in[13];
  const float* zw   = (const float*)d_in[14];
  float* out = (float*)d_out;

  k_seq<<<dim3(256), dim3(512), 0, stream>>>(in, Wih, Whh, bih, bhh,
                                             fc1w, fc1b, fc2w, fc2b,
                                             i1w, i1b, i3w, i3b, scw, zw, out);
}

// Round 10
// 1080.264 us; speedup vs baseline: 1.8457x; 1.1369x over previous
//
#include <hip/hip_runtime.h>

#define BT   (512*256)
// hbuf (bytes): zeros @0..127, b0 h @128..255, b1 h @288..415
#define HB0b 128
#define HB1b 288
#define HLENb 448

using short8  = __attribute__((ext_vector_type(8))) short;
using floatx4 = __attribute__((ext_vector_type(4))) float;
using int4v   = __attribute__((ext_vector_type(4))) int;

__device__ inline unsigned short f2bf(float f){
  unsigned int u = __float_as_uint(f);
  u += 0x7FFFu + ((u >> 16) & 1u);          // RNE
  return (unsigned short)(u >> 16);
}
__device__ inline float bf2f(unsigned short u){
  return __uint_as_float(((unsigned int)u) << 16);
}
__device__ inline float rcpf(float x){ return __builtin_amdgcn_rcpf(x); }

// 256 blocks x 512 threads = 8 waves (2/SIMD), __launch_bounds__(512,1) ->
// 256-VGPR cap, no spill (round 9: VGPR=112). Gate matmul in INT8 MFMA
// (mfma_i32_16x16x64_i8): K=128 in 2 instructions -> half the bf16 MFMA-issue
// floor (320 vs 620 cyc/SIMD/step). h quantized to i8 (h in (-1,1), scale
// 127); W_hh/fc1w quantized per-row (scale 127/rowmax); i32 accumulation is
// exact; dequant = acc * rowmax/127^2. x-gates/biases remain f32/bf16.
// A rows {0,4,8,12}={b0,b1,b0,b1}: lane(quad,l15) gets all 4 gates of
// (batch=quad&1, unit=16wv+l15) natively in acc[g][0]; quads 2/3 duplicate.
// E-update deferred into next iter's phase A (E lives in every lane's regs)
// -> 10 barriers/outer, E-phase barrier eliminated. No global ops in loop.
__global__ __launch_bounds__(512,1) void k_seq(
    const float* __restrict__ in,
    const float* __restrict__ Wih,  const float* __restrict__ Whh,
    const float* __restrict__ bih,  const float* __restrict__ bhh,
    const float* __restrict__ fc1w, const float* __restrict__ fc1b,
    const float* __restrict__ fc2w, const float* __restrict__ fc2b,
    const float* __restrict__ i1w,  const float* __restrict__ i1b,
    const float* __restrict__ i3w,  const float* __restrict__ i3b,
    const float* __restrict__ scw,  const float* __restrict__ zonew,
    float* __restrict__ out)
{
  __shared__ __align__(16) signed char hbuf[2][HLENb];     // 896 B i8 h
  __shared__ __align__(16) unsigned short xg[8192];        // 16 KB bf16 gates (+init scratch)
  __shared__ __align__(8)  unsigned short toutl[512];      // bf16 TOut history [b][256]
  __shared__ __align__(8)  unsigned short extl[512];       // bf16 Ext results [b][256]
  __shared__ __align__(16) unsigned short exl[2048];       // bf16 Ext_X cols [b*256+t][4]
  __shared__ float t0l[512];                               // T0 f32
  __shared__ float hvitl[512];                             // HVAC + int_all f32
  __shared__ float parts[16];                              // fc2 wave partials [wv][b]

  const int tid = threadIdx.x;
  const int wv  = tid >> 6;             // 0..7
  const int ln  = tid & 63;
  const int l15 = ln & 15;
  const int quad= ln >> 4;
  const int bb  = blockIdx.x;

  // ---- init: stage per-block tables ----
  {
    int b=tid>>8, tt=tid&255;
    const float* row = in + (2*bb+b)*1792 + tt*7;
    t0l[tid] = row[0];
    exl[tid*4+0]=f2bf(row[1]); exl[tid*4+1]=f2bf(row[2]);
    exl[tid*4+2]=f2bf(row[3]); exl[tid*4+3]=f2bf(row[4]);
  }
  for(int p=tid; p<2*HLENb; p+=512) ((signed char*)hbuf)[p]=0;
  if(tid<16) toutl[(tid>>3)*256+(tid&7)] = f2bf(in[(2*bb+(tid>>3))*1792+(tid&7)*7]);
  float* lw4 = (float*)&xg[0];          // int-module scratch (region reused later)
  float* l3  = lw4 + 512;
  if(tid<128){
    lw4[tid*4+0]=i1w[tid*3+0]; lw4[tid*4+1]=i1w[tid*3+1];
    lw4[tid*4+2]=i1w[tid*3+2]; lw4[tid*4+3]=i1b[tid];
    l3[tid]=i3w[tid];
  }
  __syncthreads();
  if(tid<256) hbuf[0][((tid>>7)? HB1b:HB0b) + (tid&127)] = 127;   // h=1.0 -> q=127

  // ---- fused int module (one (b,t) per thread) ----
  {
    const float b30=i3b[0], sc0=scw[0];
    int b=tid>>8, t=tid&255;
    const float* row = in + (2*bb+b)*1792 + t*7;
    float x0=row[3],x1=row[4],x2=row[5], acc=0.f;
    #pragma unroll 8
    for(int j=0;j<128;j++){
      float r=fmaxf(lw4[j*4]*x0+lw4[j*4+1]*x1+lw4[j*4+2]*x2+lw4[j*4+3],0.f);
      acc += r*l3[j];
    }
    float v = rcpf(1.f+__expf(-(acc+b30)))*sc0;
    float itv = (t<8)?0.f:v;
    int gb = 2*bb+b;
    hvitl[tid] = row[6] + itv;
    out[3*BT+gb*256+t]=itv;              // Int_list
    out[BT+gb*256+t]=row[6];             // HVAC_list
    if(t<8){ out[gb*256+t]=row[0]; out[2*BT+gb*256+t]=0.f; }
  }

  // ---- i8 weight quantization (per-row scale) into VGPRs ----
  int4v wq[4][2];        // [gate][K-chunk], rows n = 128g + 16wv + l15
  float dq[4];
  short8 xfr[4];         // W_ih bf16, K=32 pad (5 valid)
  float  bsum[4];
  #pragma unroll
  for(int g=0;g<4;g++){
    int n = 128*g + 16*wv + l15;
    bsum[g] = bih[n]+bhh[n];
    const float* wr = Whh + n*128;
    float mx = 1e-20f;
    for(int j=0;j<128;j++) mx = fmaxf(mx, fabsf(wr[j]));
    float qs = 127.f/mx;
    dq[g] = mx * (1.f/16129.f);          // 1/127^2
    #pragma unroll
    for(int c=0;c<2;c++){
      int4v v4;
      #pragma unroll
      for(int d=0;d<4;d++){
        int pk=0;
        #pragma unroll
        for(int bq=0;bq<4;bq++){
          int kk = c*64 + quad*16 + d*4 + bq;
          int q = __float2int_rn(wr[kk]*qs);
          pk |= (q & 255) << (8*bq);
        }
        v4[d]=pk;
      }
      wq[g][c]=v4;
    }
    short8 f;
    #pragma unroll
    for(int j=0;j<8;j++){ int kk=quad*8+j; f[j]=(short)f2bf(kk<5?Wih[n*5+kk]:0.f); }
    xfr[g]=f;
  }
  int4v fq[2]; float dqf;                // fc1 i8, row n2 = 16wv + l15
  {
    int n2 = 16*wv + l15;
    const float* fr = fc1w + n2*128;
    float mx = 1e-20f;
    for(int j=0;j<128;j++) mx = fmaxf(mx, fabsf(fr[j]));
    float qs = 127.f/mx;
    dqf = mx * (1.f/16129.f);
    #pragma unroll
    for(int c=0;c<2;c++){
      int4v v4;
      #pragma unroll
      for(int d=0;d<4;d++){
        int pk=0;
        #pragma unroll
        for(int bq=0;bq<4;bq++){
          int kk = c*64 + quad*16 + d*4 + bq;
          int q = __float2int_rn(fr[kk]*qs);
          pk |= (q & 255) << (8*bq);
        }
        v4[d]=pk;
      }
      fq[c]=v4;
    }
  }

  // ---- per-lane persistent scalars ----
  const int  u     = 16*wv + l15;           // this lane's unit
  const int  bm    = quad & 1;              // this lane's batch (quads 2/3 dup)
  const int  arow  = ((l15&3)==0) ? (((l15>>2)&1)? HB1b : HB0b) : 0;  // 0 = zero region
  const int  aoff  = arow + quad*16;
  const int  xbase = bm*512 + u;
  const int  hwoff = (bm? HB1b:HB0b) + u;
  const float fb    = fc1b[u];
  const float fcw_u = fc2w[u];
  const float fc2b0 = fc2b[0];
  const float zwv   = zonew[0];
  const floatx4 ZV  = {0.f,0.f,0.f,0.f};
  const int4v   ZI  = {0,0,0,0};
  const short8  Z8  = 0;
  float E0 = in[(2*bb)*1792 + 56];          // E in EVERY lane's registers
  float E1 = in[(2*bb+1)*1792 + 56];
  float c0 = 1.f;
  __syncthreads();                          // int scratch retired -> xg reusable

  #pragma unroll 1
  for(int i=8;i<256;i++){
    // ===== phase A: deferred E-update (i-1), TOut, embed, x-MFMA =====
    if(i>8){
      float ext0 = parts[0]+parts[2]+parts[4]+parts[6]
                 + parts[8]+parts[10]+parts[12]+parts[14] + fc2b0;
      float ext1 = parts[1]+parts[3]+parts[5]+parts[7]
                 + parts[9]+parts[11]+parts[13]+parts[15] + fc2b0;
      int ip = i-1;
      float tot0 = ext0 + hvitl[ip];
      float tot1 = ext1 + hvitl[256+ip];
      if(ip<128){
        float ratio=(float)ip*0.0078125f;
        E0 = ratio*t0l[ip]     + (1.f-ratio)*E0 + tot0*zwv;
        E1 = ratio*t0l[256+ip] + (1.f-ratio)*E1 + tot1*zwv;
      } else {
        E0 += tot0*zwv;
        E1 += tot1*zwv;
      }
      if(tid==0){ extl[ip]=f2bf(ext0); extl[256+ip]=f2bf(ext1); }
    }
    if(tid==0){ toutl[i]=f2bf(E0); toutl[256+i]=f2bf(E1); }   // TOut[:,i]=E
    {
      short8 ea = Z8;
      if(quad==0){
        int bE=l15>>3, kk=l15&7, p=i-7+kk;
        float tos = (p==i) ? (bE? E1:E0) : bf2f(toutl[bE*256+p]);
        float tmix;
        if(i<128){
          float ratio=(float)i*0.0078125f;
          tmix = t0l[bE*256+p]*ratio + tos*(1.f-ratio);
        } else tmix = tos;
        ea[0]=(short)f2bf(tmix);
        ea[1]=(short)exl[(bE*256+p)*4+0]; ea[2]=(short)exl[(bE*256+p)*4+1];
        ea[3]=(short)exl[(bE*256+p)*4+2]; ea[4]=(short)exl[(bE*256+p)*4+3];
      }
      #pragma unroll
      for(int g=0;g<4;g++){
        floatx4 z=__builtin_amdgcn_mfma_f32_16x16x32_bf16(ea, xfr[g], ZV,0,0,0);
        #pragma unroll
        for(int r=0;r<4;r++){
          int m=4*quad+r;                    // m = b*8+k
          xg[(m&7)*1024 + (m>>3)*512 + 128*g + u] = f2bf(z[r]+bsum[g]);
        }
      }
    }
    __syncthreads();

    // ===== 8 inner LSTM steps: 8 i8 MFMAs/wave, single nonlin chain =====
    #pragma unroll
    for(int k=0;k<8;k++){
      float xv0=bf2f(xg[k*1024+xbase    ]);
      float xv1=bf2f(xg[k*1024+xbase+128]);
      float xv2=bf2f(xg[k*1024+xbase+256]);
      float xv3=bf2f(xg[k*1024+xbase+384]);
      const signed char* hb = &hbuf[k&1][0];
      int4v a0 = *(const int4v*)(hb + aoff);        // K 0..63
      int4v a1 = *(const int4v*)(hb + aoff + 64);   // K 64..127
      int4v acc[4];
      #pragma unroll
      for(int g=0;g<4;g++){
        int4v z = __builtin_amdgcn_mfma_i32_16x16x64_i8(a0, wq[g][0], ZI,0,0,0);
        z = __builtin_amdgcn_mfma_i32_16x16x64_i8(a1, wq[g][1], z,0,0,0);
        acc[g]=z;
      }
      float gi=(float)acc[0][0]*dq[0]+xv0;
      float gf=(float)acc[1][0]*dq[1]+xv1;
      float gg=(float)acc[2][0]*dq[2]+xv2;
      float go=(float)acc[3][0]*dq[3]+xv3;
      float ef =__expf(-gf);
      float egi=__expf(-gi);
      float egg=__expf(-2.f*gg);
      float sf = rcpf(1.f+ef);
      float itn=(1.f-egg)*rcpf((1.f+egi)*(1.f+egg));
      c0 = sf*c0 + itn;
      float ego=__expf(-go);
      float ec =__expf(-2.f*c0);
      float hv2=(1.f-ec)*rcpf((1.f+ego)*(1.f+ec));
      int q = __float2int_rn(hv2*127.f);            // |h|<1 -> |q|<=127
      hbuf[(k+1)&1][hwoff] = (signed char)q;        // quads 2/3 dup same value
      __syncthreads();
    }

    // ===== fc1 (i8) + in-register fc2 partial reduce =====
    {
      const signed char* hb = &hbuf[0][0];
      int4v a0 = *(const int4v*)(hb + aoff);
      int4v a1 = *(const int4v*)(hb + aoff + 64);
      int4v z = __builtin_amdgcn_mfma_i32_16x16x64_i8(a0, fq[0], ZI,0,0,0);
      z = __builtin_amdgcn_mfma_i32_16x16x64_i8(a1, fq[1], z,0,0,0);
      float fv = (float)z[0]*dqf + fb;
      float pv = fmaxf(fv,0.f)*fcw_u;
      float v0 = (quad==0) ? pv : 0.f;              // quads 2/3 dups excluded
      float v1 = (quad==1) ? pv : 0.f;
      #pragma unroll
      for(int off=32; off; off>>=1){
        v0 += __shfl_xor(v0, off, 64);
        v1 += __shfl_xor(v1, off, 64);
      }
      if(ln==0){ parts[wv*2]=v0; parts[wv*2+1]=v1; }
    }
    __syncthreads();
  }

  // ===== tail: ext(255) from last fc =====
  if(tid==0){
    float ext0 = parts[0]+parts[2]+parts[4]+parts[6]
               + parts[8]+parts[10]+parts[12]+parts[14] + fc2b0;
    float ext1 = parts[1]+parts[3]+parts[5]+parts[7]
               + parts[9]+parts[11]+parts[13]+parts[15] + fc2b0;
    extl[255]=f2bf(ext0); extl[511]=f2bf(ext1);
  }
  __syncthreads();

  // ===== flush TOut / Ext_list from LDS =====
  for(int p=tid; p<496; p+=512){
    int b = (p>=248) ? 1 : 0;
    int i2 = p - b*248 + 8;
    int gb = 2*bb + b;
    out[gb*256+i2]      = bf2f(toutl[b*256+i2]);
    out[2*BT+gb*256+i2] = bf2f(extl[b*256+i2]);
  }
}

extern "C" void kernel_launch(void* const* d_in, const int* in_sizes, int n_in,
                              void* d_out, int out_size, void* d_ws, size_t ws_size,
                              hipStream_t stream)
{
  const float* in   = (const float*)d_in[0];
  const float* Wih  = (const float*)d_in[1];
  const float* Whh  = (const float*)d_in[2];
  const float* bih  = (const float*)d_in[3];
  const float* bhh  = (const float*)d_in[4];
  const float* fc1w = (const float*)d_in[5];
  const float* fc1b = (const float*)d_in[6];
  const float* fc2w = (const float*)d_in[7];
  const float* fc2b = (const float*)d_in[8];
  const float* i1w  = (const float*)d_in[9];
  const float* i1b  = (const float*)d_in[10];
  const float* i3w  = (const float*)d_in[11];
  const float* i3b  = (const float*)d_in[12];
  const float* scw  = (const float*)d_in[13];
  const float* zw   = (const float*)d_in[14];
  float* out = (float*)d_out;

  k_seq<<<dim3(256), dim3(512), 0, stream>>>(in, Wih, Whh, bih, bhh,
                                             fc1w, fc1b, fc2w, fc2b,
                                             i1w, i1b, i3w, i3b, scw, zw, out);
}